// Round 4
// baseline (235.148 us; speedup 1.0000x reference)
//
#include <hip/hip_runtime.h>
#include <math.h>

// PillarAttentionClassifier — R4: R3 with compile fix (__int_as_float).
// Fused per-wave MFMA pipeline, f16 in / fp32 acc; 2 tiles in flight per wave,
// x prefetched one pair ahead, DPP row_ror reductions (VALU) for softmax and
// final dot, rep A-frags read once shared by attention+W1, h2 aliases rep LDS,
// float4 coalesced output stores. No barriers (per-wave private LDS).

typedef _Float16 f16x8 __attribute__((ext_vector_type(8)));
typedef float    f32x4 __attribute__((ext_vector_type(4)));

#define EPS 1e-5f

__device__ __forceinline__ float rcp_fast(float v) { return __builtin_amdgcn_rcpf(v); }

template<int N>
__device__ __forceinline__ float dpp_ror(float v) {
    return __int_as_float(__builtin_amdgcn_update_dpp(
        0, __float_as_int(v), 0x120 + N, 0xF, 0xF, true));
}
// allreduce over the 16 lanes of a DPP row (lanes 16q..16q+15)
__device__ __forceinline__ float row_sum16(float v) {
    v += dpp_ror<1>(v); v += dpp_ror<2>(v); v += dpp_ror<4>(v); v += dpp_ror<8>(v);
    return v;
}
__device__ __forceinline__ float row_max16(float v) {
    v = fmaxf(v, dpp_ror<1>(v)); v = fmaxf(v, dpp_ror<2>(v));
    v = fmaxf(v, dpp_ror<4>(v)); v = fmaxf(v, dpp_ror<8>(v));
    return v;
}

__host__ __device__ constexpr unsigned long long packGS() {
    constexpr int gs[12] = {0,3,5,7,10,12,15,17,19,20,23,26};
    unsigned long long v = 0;
    for (int g = 0; g < 12; ++g) v |= (unsigned long long)gs[g] << (5*g);
    return v;
}
__host__ __device__ constexpr unsigned packGL() {
    constexpr int gl[12] = {3,2,2,3,2,3,2,2,1,3,3,3};
    unsigned v = 0;
    for (int g = 0; g < 12; ++g) v |= (unsigned)gl[g] << (2*g);
    return v;
}

__global__ __launch_bounds__(256, 2) void fused_kernel(
    const float* __restrict__ x,
    const float* __restrict__ We,  const float* __restrict__ be,
    const float* __restrict__ eg,  const float* __restrict__ ebt,
    const float* __restrict__ em,  const float* __restrict__ ev,
    const float* __restrict__ Wa,  const float* __restrict__ ba,
    const float* __restrict__ W1,  const float* __restrict__ b1,
    const float* __restrict__ g1,  const float* __restrict__ bb1,
    const float* __restrict__ m1,  const float* __restrict__ v1,
    const float* __restrict__ W2,  const float* __restrict__ b2,
    const float* __restrict__ g2,  const float* __restrict__ bb2,
    const float* __restrict__ m2,  const float* __restrict__ v2,
    const float* __restrict__ W3,  const float* __restrict__ b3,
    const float* __restrict__ g3,  const float* __restrict__ bb3,
    const float* __restrict__ m3,  const float* __restrict__ v3,
    const float* __restrict__ W4,  const float* __restrict__ b4,
    float* __restrict__ out, int B, int ntiles)
{
    // per-wave, per-tile-slot private LDS: 6720 B/slot, 2 slots/wave, 4 waves = 53760 B
    __shared__ __align__(16) char smem_raw[53760];
    const int lane = threadIdx.x & 63;
    const int wave = threadIdx.x >> 6;
    const int l15  = lane & 15;
    const int quad = lane >> 4;

    _Float16* repT[2]; float* wT[2]; _Float16* h1T[2]; _Float16* h2T[2];
    #pragma unroll
    for (int u = 0; u < 2; ++u) {
        char* sw = smem_raw + wave * 13440 + u * 6720;
        repT[u] = (_Float16*)sw;            // [16][104] f16
        wT[u]   = (float*)   (sw + 3328);   // [16][17]  f32
        h1T[u]  = (_Float16*)(sw + 4416);   // [16][72]  f16
        h2T[u]  = (_Float16*)sw;            // [16][40]  f16, aliases repT (WAR-safe)
    }

    constexpr unsigned long long GS = packGS();
    constexpr unsigned GL = packGL();

    // ================= per-block prologue: B-frags + params (L2-resident) ========
    f16x8 Benc[6];
    #pragma unroll
    for (int t = 0; t < 6; ++t) {
        const int n = t*16 + l15;
        const int g = n >> 3, o = n & 7;
        const int gs = (int)((GS >> (5*g)) & 31);
        const int gl = (int)((GL >> (2*g)) & 3);
        #pragma unroll
        for (int j = 0; j < 8; ++j) {
            const int k  = quad*8 + j;
            const int ji = k - gs;
            float v = (ji >= 0 && ji < gl) ? We[(g*3 + ji)*8 + o] : 0.f;
            Benc[t][j] = (_Float16)v;
        }
    }
    f16x8 Bwa[3];
    #pragma unroll
    for (int s = 0; s < 3; ++s)
        #pragma unroll
        for (int j = 0; j < 8; ++j) {
            const int k = s*32 + quad*8 + j;
            Bwa[s][j] = (_Float16)((l15 < 12) ? Wa[k*12 + l15] : 0.f);
        }
    f16x8 Bw1[12];
    #pragma unroll
    for (int t = 0; t < 4; ++t)
        #pragma unroll
        for (int s = 0; s < 3; ++s)
            #pragma unroll
            for (int j = 0; j < 8; ++j) {
                const int k = s*32 + quad*8 + j;
                Bw1[t*3 + s][j] = (_Float16)W1[k*64 + t*16 + l15];
            }
    f16x8 Bw2[4];
    #pragma unroll
    for (int t = 0; t < 2; ++t)
        #pragma unroll
        for (int s = 0; s < 2; ++s)
            #pragma unroll
            for (int j = 0; j < 8; ++j) {
                const int k = s*32 + quad*8 + j;
                Bw2[t*2 + s][j] = (_Float16)W2[k*32 + t*16 + l15];
            }
    f16x8 Bw3;
    #pragma unroll
    for (int j = 0; j < 8; ++j)
        Bw3[j] = (_Float16)W3[(quad*8 + j)*16 + l15];

    float encB[6], encS[6], encT[6];
    #pragma unroll
    for (int t = 0; t < 6; ++t) {
        const int c = t*16 + l15;
        float s = eg[c] * rsqrtf(ev[c] + EPS);
        encS[t] = s; encT[t] = ebt[c] - em[c]*s; encB[t] = be[c];
    }
    const float baL = (l15 < 12) ? ba[l15] : -1e4f;   // pad cols -> weight ~0
    float b1L[4], s1L[4], t1L[4];
    #pragma unroll
    for (int t = 0; t < 4; ++t) {
        const int c = t*16 + l15;
        float s = g1[c] * rsqrtf(v1[c] + EPS);
        s1L[t] = s; t1L[t] = bb1[c] - m1[c]*s; b1L[t] = b1[c];
    }
    float b2L[2], s2L[2], t2L[2];
    #pragma unroll
    for (int t = 0; t < 2; ++t) {
        const int c = t*16 + l15;
        float s = g2[c] * rsqrtf(v2[c] + EPS);
        s2L[t] = s; t2L[t] = bb2[c] - m2[c]*s; b2L[t] = b2[c];
    }
    const float sv3 = g3[l15] * rsqrtf(v3[l15] + EPS);
    const float b3L = b3[l15], s3L = sv3, t3L = bb3[l15] - m3[l15]*sv3;
    const float w4L = W4[l15];
    const float b4v = b4[0];

    // ================= main loop: 32 tiles/block, pair of tiles per iteration ====
    const int tbase = blockIdx.x * 32 + wave * 2;

    auto loadx = [&](int pp, float (&xv)[2][8]) {
        #pragma unroll
        for (int u = 0; u < 2; ++u) {
            int tl = tbase + 8*pp + u; if (tl > ntiles-1) tl = ntiles-1;
            int xr = tl*16 + l15;      if (xr > B-1)      xr = B-1;
            const float* xp = x + (size_t)xr*29 + quad*8;
            if (quad < 3) {
                #pragma unroll
                for (int j = 0; j < 8; ++j) xv[u][j] = xp[j];
            } else {
                #pragma unroll
                for (int j = 0; j < 5; ++j) xv[u][j] = xp[j];
                xv[u][5] = xv[u][6] = xv[u][7] = 0.f;
            }
        }
    };

    float xcur[2][8];
    loadx(0, xcur);

    #pragma unroll 1
    for (int p = 0; p < 4; ++p) {
        // ---- prefetch next pair's x (hides HBM latency behind this pair) ----
        float xnext[2][8];
        loadx(p < 3 ? p + 1 : 3, xnext);

        // ---- cvt x to f16 A-frags ----
        f16x8 ax[2];
        #pragma unroll
        for (int u = 0; u < 2; ++u)
            #pragma unroll
            for (int j = 0; j < 8; ++j) ax[u][j] = (_Float16)xcur[u][j];

        // ---- stage 1: rep = BNaff(relu(x @ Wenc + be)) -> LDS ----
        #pragma unroll
        for (int u = 0; u < 2; ++u)
            #pragma unroll
            for (int t = 0; t < 6; ++t) {
                f32x4 c = { encB[t], encB[t], encB[t], encB[t] };
                c = __builtin_amdgcn_mfma_f32_16x16x32_f16(ax[u], Benc[t], c, 0, 0, 0);
                #pragma unroll
                for (int r = 0; r < 4; ++r)
                    repT[u][(quad*4 + r)*104 + t*16 + l15] =
                        (_Float16)fmaf(fmaxf(c[r], 0.f), encS[t], encT[t]);
            }

        // ---- stages 2+3: read rep A-frags ONCE; attention softmax (DPP); W1 ----
        f16x8 afr[2][3];
        #pragma unroll
        for (int u = 0; u < 2; ++u)
            #pragma unroll
            for (int s = 0; s < 3; ++s)
                afr[u][s] = *(const f16x8*)(repT[u] + l15*104 + s*32 + quad*8);

        #pragma unroll
        for (int u = 0; u < 2; ++u) {
            f32x4 c2 = { baL, baL, baL, baL };
            #pragma unroll
            for (int s = 0; s < 3; ++s)
                c2 = __builtin_amdgcn_mfma_f32_16x16x32_f16(afr[u][s], Bwa[s], c2, 0, 0, 0);
            #pragma unroll
            for (int r = 0; r < 4; ++r) {
                float v  = c2[r];
                float mx = row_max16(v);
                float e  = __expf(v - mx);
                float sm = row_sum16(e);
                wT[u][(quad*4 + r)*17 + l15] = e * rcp_fast(sm);
            }
        }

        #pragma unroll
        for (int u = 0; u < 2; ++u) {
            f32x4 c3[4];
            #pragma unroll
            for (int t = 0; t < 4; ++t) c3[t] = { b1L[t], b1L[t], b1L[t], b1L[t] };
            #pragma unroll
            for (int s = 0; s < 3; ++s) {
                _Float16 wh = (_Float16)wT[u][l15*17 + s*4 + quad];  // group = s*4+quad
                f16x8 aw;
                #pragma unroll
                for (int j = 0; j < 8; ++j) aw[j] = afr[u][s][j] * wh;
                #pragma unroll
                for (int t = 0; t < 4; ++t)
                    c3[t] = __builtin_amdgcn_mfma_f32_16x16x32_f16(aw, Bw1[t*3 + s], c3[t], 0, 0, 0);
            }
            #pragma unroll
            for (int t = 0; t < 4; ++t)
                #pragma unroll
                for (int r = 0; r < 4; ++r)
                    h1T[u][(quad*4 + r)*72 + t*16 + l15] =
                        (_Float16)fmaf(fmaxf(c3[t][r], 0.f), s1L[t], t1L[t]);
        }

        // ---- stage 4: h2 = BNaff(relu(h1 @ W2 + b2)) ----
        #pragma unroll
        for (int u = 0; u < 2; ++u) {
            f32x4 c4[2];
            #pragma unroll
            for (int t = 0; t < 2; ++t) c4[t] = { b2L[t], b2L[t], b2L[t], b2L[t] };
            #pragma unroll
            for (int s = 0; s < 2; ++s) {
                f16x8 a = *(const f16x8*)(h1T[u] + l15*72 + s*32 + quad*8);
                #pragma unroll
                for (int t = 0; t < 2; ++t)
                    c4[t] = __builtin_amdgcn_mfma_f32_16x16x32_f16(a, Bw2[t*2 + s], c4[t], 0, 0, 0);
            }
            #pragma unroll
            for (int t = 0; t < 2; ++t)
                #pragma unroll
                for (int r = 0; r < 4; ++r)
                    h2T[u][(quad*4 + r)*40 + t*16 + l15] =
                        (_Float16)fmaf(fmaxf(c4[t][r], 0.f), s2L[t], t2L[t]);
        }

        // ---- stages 5+6: h3 MFMA; z = bnrelu(h3) . W4 via DPP row-sum; store ----
        #pragma unroll
        for (int u = 0; u < 2; ++u) {
            f32x4 c5 = { b3L, b3L, b3L, b3L };
            f16x8 a = *(const f16x8*)(h2T[u] + l15*40 + quad*8);
            c5 = __builtin_amdgcn_mfma_f32_16x16x32_f16(a, Bw3, c5, 0, 0, 0);

            float z[4];
            #pragma unroll
            for (int r = 0; r < 4; ++r) {
                float v = fmaf(fmaxf(c5[r], 0.f), s3L, t3L);
                z[r] = row_sum16(v * w4L);
            }
            const int tl = tbase + 8*p + u;
            if (l15 == 0 && tl < ntiles) {
                float4 o;
                o.x = rcp_fast(1.f + __expf(-(z[0] + b4v)));
                o.y = rcp_fast(1.f + __expf(-(z[1] + b4v)));
                o.z = rcp_fast(1.f + __expf(-(z[2] + b4v)));
                o.w = rcp_fast(1.f + __expf(-(z[3] + b4v)));
                *(float4*)(out + tl*16 + quad*4) = o;
            }
        }

        // ---- rotate prefetch ----
        #pragma unroll
        for (int u = 0; u < 2; ++u)
            #pragma unroll
            for (int j = 0; j < 8; ++j) xcur[u][j] = xnext[u][j];
    }
}

extern "C" void kernel_launch(void* const* d_in, const int* in_sizes, int n_in,
                              void* d_out, int out_size, void* d_ws, size_t ws_size,
                              hipStream_t stream)
{
    const float* x   = (const float*)d_in[0];
    const float* We  = (const float*)d_in[1];
    const float* be  = (const float*)d_in[2];
    const float* eg  = (const float*)d_in[3];
    const float* ebt = (const float*)d_in[4];
    const float* em  = (const float*)d_in[5];
    const float* ev  = (const float*)d_in[6];
    const float* Wa  = (const float*)d_in[7];
    const float* ba  = (const float*)d_in[8];
    const float* W1  = (const float*)d_in[9];
    const float* b1  = (const float*)d_in[10];
    const float* g1  = (const float*)d_in[11];
    const float* bb1 = (const float*)d_in[12];
    const float* m1  = (const float*)d_in[13];
    const float* v1  = (const float*)d_in[14];
    const float* W2  = (const float*)d_in[15];
    const float* b2  = (const float*)d_in[16];
    const float* g2  = (const float*)d_in[17];
    const float* bb2 = (const float*)d_in[18];
    const float* m2  = (const float*)d_in[19];
    const float* v2  = (const float*)d_in[20];
    const float* W3  = (const float*)d_in[21];
    const float* b3  = (const float*)d_in[22];
    const float* g3  = (const float*)d_in[23];
    const float* bb3 = (const float*)d_in[24];
    const float* m3  = (const float*)d_in[25];
    const float* v3  = (const float*)d_in[26];
    const float* W4  = (const float*)d_in[27];
    const float* b4  = (const float*)d_in[28];

    const int B = in_sizes[0] / 29;
    const int ntiles = (B + 15) / 16;
    const int blocks = (ntiles + 31) / 32;   // 32 tiles per block, 8 per wave

    fused_kernel<<<blocks, 256, 0, stream>>>(
        x, We, be, eg, ebt, em, ev, Wa, ba,
        W1, b1, g1, bb1, m1, v1,
        W2, b2, g2, bb2, m2, v2,
        W3, b3, g3, bb3, m3, v3,
        W4, b4, (float*)d_out, B, ntiles);
}

// Round 6
// 212.186 us; speedup vs baseline: 1.1082x; 1.1082x over previous
//
#include <hip/hip_runtime.h>
#include <math.h>

// PillarAttentionClassifier — R6: R5 with pkrtz bit-cast compile fix.
// Per-wave MFMA pipeline, ILP=1 (no-spill), DPP row_ror reductions,
// x prefetched 1 ahead, permuted feature storage so LDS epilogue writes are
// packed (b32/b64); B-frag rows permuted to match at prologue.
//    rep perm: n' = (t%3)*32 + c*2 + t/3   (n = t*16+c, t=0..5)
//    h1  perm: n' = c*4 + t                (n = t*16+c, t=0..3)
//    h2  perm: n' = c*2 + t                (n = t*16+c, t=0..1)
//  attention scale per A-frag element: group g = 2s + 6*(j&1) + (quad>=2)
// Layouts: A[m=lane&15][k=quad*8+j], C/D: col=lane&15, row=quad*4+reg.

typedef _Float16 f16x8 __attribute__((ext_vector_type(8)));
typedef _Float16 f16x4 __attribute__((ext_vector_type(4)));
typedef _Float16 f16x2 __attribute__((ext_vector_type(2)));
typedef float    f32x4 __attribute__((ext_vector_type(4)));

#define EPS 1e-5f

__device__ __forceinline__ float rcp_fast(float v) { return __builtin_amdgcn_rcpf(v); }

__device__ __forceinline__ f16x2 pkrtz(float a, float b) {
    return __builtin_bit_cast(f16x2, __builtin_amdgcn_cvt_pkrtz(a, b));
}

template<int N>
__device__ __forceinline__ float dpp_ror(float v) {
    return __int_as_float(__builtin_amdgcn_update_dpp(
        0, __float_as_int(v), 0x120 + N, 0xF, 0xF, true));
}
__device__ __forceinline__ float row_sum16(float v) {
    v += dpp_ror<1>(v); v += dpp_ror<2>(v); v += dpp_ror<4>(v); v += dpp_ror<8>(v);
    return v;
}
__device__ __forceinline__ float row_max16(float v) {
    v = fmaxf(v, dpp_ror<1>(v)); v = fmaxf(v, dpp_ror<2>(v));
    v = fmaxf(v, dpp_ror<4>(v)); v = fmaxf(v, dpp_ror<8>(v));
    return v;
}

// storage-index -> original-feature maps (must match write-side packing)
__device__ __forceinline__ int perm96(int k) {   // rep: k' -> n
    return ((k >> 5) + 3 * (k & 1)) * 16 + ((k & 31) >> 1);
}
__device__ __forceinline__ int perm64(int k) {   // h1
    return (k & 3) * 16 + (k >> 2);
}
__device__ __forceinline__ int perm32(int k) {   // h2
    return (k & 1) * 16 + (k >> 1);
}

__host__ __device__ constexpr unsigned long long packGS() {
    constexpr int gs[12] = {0,3,5,7,10,12,15,17,19,20,23,26};
    unsigned long long v = 0;
    for (int g = 0; g < 12; ++g) v |= (unsigned long long)gs[g] << (5*g);
    return v;
}
__host__ __device__ constexpr unsigned packGL() {
    constexpr int gl[12] = {3,2,2,3,2,3,2,2,1,3,3,3};
    unsigned v = 0;
    for (int g = 0; g < 12; ++g) v |= (unsigned)gl[g] << (2*g);
    return v;
}

__global__ __launch_bounds__(256, 2) void fused_kernel(
    const float* __restrict__ x,
    const float* __restrict__ We,  const float* __restrict__ be,
    const float* __restrict__ eg,  const float* __restrict__ ebt,
    const float* __restrict__ em,  const float* __restrict__ ev,
    const float* __restrict__ Wa,  const float* __restrict__ ba,
    const float* __restrict__ W1,  const float* __restrict__ b1,
    const float* __restrict__ g1,  const float* __restrict__ bb1,
    const float* __restrict__ m1,  const float* __restrict__ v1,
    const float* __restrict__ W2,  const float* __restrict__ b2,
    const float* __restrict__ g2,  const float* __restrict__ bb2,
    const float* __restrict__ m2,  const float* __restrict__ v2,
    const float* __restrict__ W3,  const float* __restrict__ b3,
    const float* __restrict__ g3,  const float* __restrict__ bb3,
    const float* __restrict__ m3,  const float* __restrict__ v3,
    const float* __restrict__ W4,  const float* __restrict__ b4,
    float* __restrict__ out, int B, int ntiles)
{
    // per-wave private LDS: rep 3328 | wT 1088 | h1 2304 | h2 1280 = 8000 B
    __shared__ __align__(16) char smem_raw[32000];
    const int lane = threadIdx.x & 63;
    const int wave = threadIdx.x >> 6;
    const int l15  = lane & 15;
    const int quad = lane >> 4;
    const int qh   = quad >> 1;          // (quad >= 2)

    char* sw = smem_raw + wave * 8000;
    _Float16* rep = (_Float16*)sw;            // [16][104] f16, 96 used (permuted)
    float*    wTb = (float*)   (sw + 3328);   // [16][17]  f32
    _Float16* h1b = (_Float16*)(sw + 4416);   // [16][72]  f16, 64 used (permuted)
    _Float16* h2b = (_Float16*)(sw + 6720);   // [16][40]  f16, 32 used (permuted)

    constexpr unsigned long long GS = packGS();
    constexpr unsigned GL = packGL();

    // ================= prologue: B-frags + per-lane params (L2-resident) ========
    f16x8 Benc[6];                       // cols n = t*16+l15 (unpermuted)
    #pragma unroll
    for (int t = 0; t < 6; ++t) {
        const int n = t*16 + l15;
        const int g = n >> 3, o = n & 7;
        const int gs = (int)((GS >> (5*g)) & 31);
        const int gl = (int)((GL >> (2*g)) & 3);
        #pragma unroll
        for (int j = 0; j < 8; ++j) {
            const int k  = quad*8 + j;
            const int ji = k - gs;
            Benc[t][j] = (_Float16)((ji >= 0 && ji < gl) ? We[(g*3 + ji)*8 + o] : 0.f);
        }
    }
    f16x8 Bwa[3];                        // rows permuted by perm96
    #pragma unroll
    for (int s = 0; s < 3; ++s)
        #pragma unroll
        for (int j = 0; j < 8; ++j) {
            const int n = perm96(s*32 + quad*8 + j);
            Bwa[s][j] = (_Float16)((l15 < 12) ? Wa[n*12 + l15] : 0.f);
        }
    f16x8 Bw1[12];                       // rows permuted by perm96
    #pragma unroll
    for (int t = 0; t < 4; ++t)
        #pragma unroll
        for (int s = 0; s < 3; ++s)
            #pragma unroll
            for (int j = 0; j < 8; ++j) {
                const int n = perm96(s*32 + quad*8 + j);
                Bw1[t*3 + s][j] = (_Float16)W1[n*64 + t*16 + l15];
            }
    f16x8 Bw2[4];                        // rows permuted by perm64
    #pragma unroll
    for (int t = 0; t < 2; ++t)
        #pragma unroll
        for (int s = 0; s < 2; ++s)
            #pragma unroll
            for (int j = 0; j < 8; ++j) {
                const int n = perm64(s*32 + quad*8 + j);
                Bw2[t*2 + s][j] = (_Float16)W2[n*32 + t*16 + l15];
            }
    f16x8 Bw3;                           // rows permuted by perm32
    #pragma unroll
    for (int j = 0; j < 8; ++j)
        Bw3[j] = (_Float16)W3[perm32(quad*8 + j)*16 + l15];

    float encB[6], encS[6], encT[6];
    #pragma unroll
    for (int t = 0; t < 6; ++t) {
        const int c = t*16 + l15;
        float s = eg[c] * rsqrtf(ev[c] + EPS);
        encS[t] = s; encT[t] = ebt[c] - em[c]*s; encB[t] = be[c];
    }
    const float baL = (l15 < 12) ? ba[l15] : -1e4f;
    float b1L[4], s1L[4], t1L[4];
    #pragma unroll
    for (int t = 0; t < 4; ++t) {
        const int c = t*16 + l15;
        float s = g1[c] * rsqrtf(v1[c] + EPS);
        s1L[t] = s; t1L[t] = bb1[c] - m1[c]*s; b1L[t] = b1[c];
    }
    float b2L[2], s2L[2], t2L[2];
    #pragma unroll
    for (int t = 0; t < 2; ++t) {
        const int c = t*16 + l15;
        float s = g2[c] * rsqrtf(v2[c] + EPS);
        s2L[t] = s; t2L[t] = bb2[c] - m2[c]*s; b2L[t] = b2[c];
    }
    const float sv3 = g3[l15] * rsqrtf(v3[l15] + EPS);
    const float b3L = b3[l15], s3L = sv3, t3L = bb3[l15] - m3[l15]*sv3;
    const float w4L = W4[l15];
    const float b4v = b4[0];

    // ================= main loop: 8 tiles/wave, x prefetched 1 ahead =============
    auto loadx = [&](int tl, float (&xv)[8]) {
        if (tl > ntiles-1) tl = ntiles-1;
        int xr = tl*16 + l15; if (xr > B-1) xr = B-1;
        const float* xp = x + (size_t)xr*29 + quad*8;
        if (quad < 3) {
            #pragma unroll
            for (int j = 0; j < 8; ++j) xv[j] = xp[j];
        } else {
            #pragma unroll
            for (int j = 0; j < 5; ++j) xv[j] = xp[j];
            xv[5] = xv[6] = xv[7] = 0.f;
        }
    };

    int tile = blockIdx.x * 32 + wave;
    float xf[8];
    loadx(tile, xf);

    #pragma unroll 1
    for (int p = 0; p < 8; ++p) {
        const int tnext = (p < 7) ? tile + 4 : tile;
        float xn[8];
        loadx(tnext, xn);

        f16x8 ax;
        #pragma unroll
        for (int j = 0; j < 8; ++j) ax[j] = (_Float16)xf[j];

        // ---- stage 1: rep = BNaff(relu(x @ Wenc + be)), packed-pair stores ----
        #pragma unroll
        for (int tp = 0; tp < 3; ++tp) {
            f32x4 ca = { encB[tp],   encB[tp],   encB[tp],   encB[tp]   };
            f32x4 cb = { encB[tp+3], encB[tp+3], encB[tp+3], encB[tp+3] };
            ca = __builtin_amdgcn_mfma_f32_16x16x32_f16(ax, Benc[tp],   ca, 0, 0, 0);
            cb = __builtin_amdgcn_mfma_f32_16x16x32_f16(ax, Benc[tp+3], cb, 0, 0, 0);
            #pragma unroll
            for (int r = 0; r < 4; ++r) {
                float va = fmaf(fmaxf(ca[r], 0.f), encS[tp],   encT[tp]);
                float vb = fmaf(fmaxf(cb[r], 0.f), encS[tp+3], encT[tp+3]);
                *(f16x2*)(rep + (quad*4 + r)*104 + tp*32 + l15*2) = pkrtz(va, vb);
            }
        }

        // ---- read rep A-frags once (shared by stages 2 and 3) ----
        f16x8 afr[3];
        #pragma unroll
        for (int s = 0; s < 3; ++s)
            afr[s] = *(const f16x8*)(rep + l15*104 + s*32 + quad*8);

        // ---- stage 2: logits + softmax (DPP row reductions) ----
        {
            f32x4 c2 = { baL, baL, baL, baL };
            #pragma unroll
            for (int s = 0; s < 3; ++s)
                c2 = __builtin_amdgcn_mfma_f32_16x16x32_f16(afr[s], Bwa[s], c2, 0, 0, 0);
            #pragma unroll
            for (int r = 0; r < 4; ++r) {
                float v  = c2[r];
                float mx = row_max16(v);
                float e  = __expf(v - mx);
                float sm = row_sum16(e);
                wTb[(quad*4 + r)*17 + l15] = e * rcp_fast(sm);
            }
        }

        // ---- stage 3: h1 = BNaff(relu((rep .* w) @ W1 + b1)) ----
        // afr[s][j] has group g = 2s + 6*(j&1) + qh  -> 2 w's per (lane,s)
        {
            f32x4 c3[4];
            #pragma unroll
            for (int t = 0; t < 4; ++t) c3[t] = { b1L[t], b1L[t], b1L[t], b1L[t] };
            #pragma unroll
            for (int s = 0; s < 3; ++s) {
                float we = wTb[l15*17 + 2*s + qh];
                float wo = wTb[l15*17 + 2*s + 6 + qh];
                f16x2 wpk = pkrtz(we, wo);
                f16x8 wv = { wpk[0], wpk[1], wpk[0], wpk[1],
                             wpk[0], wpk[1], wpk[0], wpk[1] };
                f16x8 aw = afr[s] * wv;
                #pragma unroll
                for (int t = 0; t < 4; ++t)
                    c3[t] = __builtin_amdgcn_mfma_f32_16x16x32_f16(aw, Bw1[t*3 + s], c3[t], 0, 0, 0);
            }
            #pragma unroll
            for (int r = 0; r < 4; ++r) {
                float v0 = fmaf(fmaxf(c3[0][r], 0.f), s1L[0], t1L[0]);
                float v1_ = fmaf(fmaxf(c3[1][r], 0.f), s1L[1], t1L[1]);
                float v2_ = fmaf(fmaxf(c3[2][r], 0.f), s1L[2], t1L[2]);
                float v3_ = fmaf(fmaxf(c3[3][r], 0.f), s1L[3], t1L[3]);
                f16x2 p0 = pkrtz(v0,  v1_);
                f16x2 p1 = pkrtz(v2_, v3_);
                f16x4 pk = { p0[0], p0[1], p1[0], p1[1] };
                *(f16x4*)(h1b + (quad*4 + r)*72 + l15*4) = pk;   // b64, 8B-aligned
            }
        }

        // ---- stage 4: h2 = BNaff(relu(h1 @ W2 + b2)) ----
        {
            f32x4 c4[2];
            #pragma unroll
            for (int t = 0; t < 2; ++t) c4[t] = { b2L[t], b2L[t], b2L[t], b2L[t] };
            #pragma unroll
            for (int s = 0; s < 2; ++s) {
                f16x8 a = *(const f16x8*)(h1b + l15*72 + s*32 + quad*8);
                #pragma unroll
                for (int t = 0; t < 2; ++t)
                    c4[t] = __builtin_amdgcn_mfma_f32_16x16x32_f16(a, Bw2[t*2 + s], c4[t], 0, 0, 0);
            }
            #pragma unroll
            for (int r = 0; r < 4; ++r) {
                float v0 = fmaf(fmaxf(c4[0][r], 0.f), s2L[0], t2L[0]);
                float v1_ = fmaf(fmaxf(c4[1][r], 0.f), s2L[1], t2L[1]);
                *(f16x2*)(h2b + (quad*4 + r)*40 + l15*2) = pkrtz(v0, v1_);
            }
        }

        // ---- stages 5+6: h3 MFMA; z = bnrelu(h3).W4 (DPP row-sum); sigmoid ----
        {
            f32x4 c5 = { b3L, b3L, b3L, b3L };
            f16x8 a = *(const f16x8*)(h2b + l15*40 + quad*8);
            c5 = __builtin_amdgcn_mfma_f32_16x16x32_f16(a, Bw3, c5, 0, 0, 0);

            float z[4];
            #pragma unroll
            for (int r = 0; r < 4; ++r) {
                float v = fmaf(fmaxf(c5[r], 0.f), s3L, t3L);
                z[r] = row_sum16(v * w4L);
            }
            if (l15 == 0 && tile < ntiles) {
                const int row = tile*16 + quad*4;
                if (row + 3 < B) {
                    float4 o;
                    o.x = rcp_fast(1.f + __expf(-(z[0] + b4v)));
                    o.y = rcp_fast(1.f + __expf(-(z[1] + b4v)));
                    o.z = rcp_fast(1.f + __expf(-(z[2] + b4v)));
                    o.w = rcp_fast(1.f + __expf(-(z[3] + b4v)));
                    *(float4*)(out + row) = o;
                } else {
                    #pragma unroll
                    for (int r = 0; r < 4; ++r)
                        if (row + r < B)
                            out[row + r] = rcp_fast(1.f + __expf(-(z[r] + b4v)));
                }
            }
        }

        tile = tnext;
        #pragma unroll
        for (int j = 0; j < 8; ++j) xf[j] = xn[j];
    }
}

extern "C" void kernel_launch(void* const* d_in, const int* in_sizes, int n_in,
                              void* d_out, int out_size, void* d_ws, size_t ws_size,
                              hipStream_t stream)
{
    const float* x   = (const float*)d_in[0];
    const float* We  = (const float*)d_in[1];
    const float* be  = (const float*)d_in[2];
    const float* eg  = (const float*)d_in[3];
    const float* ebt = (const float*)d_in[4];
    const float* em  = (const float*)d_in[5];
    const float* ev  = (const float*)d_in[6];
    const float* Wa  = (const float*)d_in[7];
    const float* ba  = (const float*)d_in[8];
    const float* W1  = (const float*)d_in[9];
    const float* b1  = (const float*)d_in[10];
    const float* g1  = (const float*)d_in[11];
    const float* bb1 = (const float*)d_in[12];
    const float* m1  = (const float*)d_in[13];
    const float* v1  = (const float*)d_in[14];
    const float* W2  = (const float*)d_in[15];
    const float* b2  = (const float*)d_in[16];
    const float* g2  = (const float*)d_in[17];
    const float* bb2 = (const float*)d_in[18];
    const float* m2  = (const float*)d_in[19];
    const float* v2  = (const float*)d_in[20];
    const float* W3  = (const float*)d_in[21];
    const float* b3  = (const float*)d_in[22];
    const float* g3  = (const float*)d_in[23];
    const float* bb3 = (const float*)d_in[24];
    const float* m3  = (const float*)d_in[25];
    const float* v3  = (const float*)d_in[26];
    const float* W4  = (const float*)d_in[27];
    const float* b4  = (const float*)d_in[28];

    const int B = in_sizes[0] / 29;
    const int ntiles = (B + 15) / 16;
    const int blocks = (ntiles + 31) / 32;   // 32 tiles/block, 8 per wave

    fused_kernel<<<blocks, 256, 0, stream>>>(
        x, We, be, eg, ebt, em, ev, Wa, ba,
        W1, b1, g1, bb1, m1, v1,
        W2, b2, g2, bb2, m2, v2,
        W3, b3, g3, bb3, m3, v3,
        W4, b4, (float*)d_out, B, ntiles);
}

// Round 7
// 200.336 us; speedup vs baseline: 1.1738x; 1.0591x over previous
//
#include <hip/hip_runtime.h>
#include <math.h>

// PillarAttentionClassifier — R7: single-wave blocks, stage-major ILP4.
// Lesson R4/R6: __launch_bounds__(256,2) => 256-reg unified budget/wave; B-frags
// go to AGPR, arch caps at 128, anything more spills to scratch (WRITE_SIZE 42MB).
// Fix: 64-thread blocks + __launch_bounds__(64,1) => full 512-reg budget, and
// latency hidden by 4 tiles in flight per wave, executed stage-major so each
// slot's dependent chain is separated by 3 independent slots' ops.
// Stage bodies reuse R6's validated code (DPP reductions, permuted packed LDS
// epilogue writes, pkrtz). Softmax max-subtraction dropped (|logit| << 88).
//    rep perm: n' = (t%3)*32 + c*2 + t/3   (n = t*16+c, t=0..5)
//    h1  perm: n' = c*4 + t ; h2 perm: n' = c*2 + t
//  attention scale per A-frag element: group g = 2s + 6*(j&1) + (quad>=2)
// Layouts: A[m=lane&15][k=quad*8+j], C/D: col=lane&15, row=quad*4+reg.

typedef _Float16 f16x8 __attribute__((ext_vector_type(8)));
typedef _Float16 f16x4 __attribute__((ext_vector_type(4)));
typedef _Float16 f16x2 __attribute__((ext_vector_type(2)));
typedef float    f32x4 __attribute__((ext_vector_type(4)));

#define EPS 1e-5f
#define NSLOT 4

__device__ __forceinline__ float rcp_fast(float v) { return __builtin_amdgcn_rcpf(v); }

__device__ __forceinline__ f16x2 pkrtz(float a, float b) {
    return __builtin_bit_cast(f16x2, __builtin_amdgcn_cvt_pkrtz(a, b));
}

template<int N>
__device__ __forceinline__ float dpp_ror(float v) {
    return __int_as_float(__builtin_amdgcn_update_dpp(
        0, __float_as_int(v), 0x120 + N, 0xF, 0xF, true));
}
__device__ __forceinline__ float row_sum16(float v) {
    v += dpp_ror<1>(v); v += dpp_ror<2>(v); v += dpp_ror<4>(v); v += dpp_ror<8>(v);
    return v;
}

// storage-index -> original-feature maps (must match write-side packing)
__device__ __forceinline__ int perm96(int k) {
    return ((k >> 5) + 3 * (k & 1)) * 16 + ((k & 31) >> 1);
}
__device__ __forceinline__ int perm64(int k) { return (k & 3) * 16 + (k >> 2); }
__device__ __forceinline__ int perm32(int k) { return (k & 1) * 16 + (k >> 1); }

__host__ __device__ constexpr unsigned long long packGS() {
    constexpr int gs[12] = {0,3,5,7,10,12,15,17,19,20,23,26};
    unsigned long long v = 0;
    for (int g = 0; g < 12; ++g) v |= (unsigned long long)gs[g] << (5*g);
    return v;
}
__host__ __device__ constexpr unsigned packGL() {
    constexpr int gl[12] = {3,2,2,3,2,3,2,2,1,3,3,3};
    unsigned v = 0;
    for (int g = 0; g < 12; ++g) v |= (unsigned)gl[g] << (2*g);
    return v;
}

__global__ __launch_bounds__(64, 1) void fused_kernel(
    const float* __restrict__ x,
    const float* __restrict__ We,  const float* __restrict__ be,
    const float* __restrict__ eg,  const float* __restrict__ ebt,
    const float* __restrict__ em,  const float* __restrict__ ev,
    const float* __restrict__ Wa,  const float* __restrict__ ba,
    const float* __restrict__ W1,  const float* __restrict__ b1,
    const float* __restrict__ g1,  const float* __restrict__ bb1,
    const float* __restrict__ m1,  const float* __restrict__ v1,
    const float* __restrict__ W2,  const float* __restrict__ b2,
    const float* __restrict__ g2,  const float* __restrict__ bb2,
    const float* __restrict__ m2,  const float* __restrict__ v2,
    const float* __restrict__ W3,  const float* __restrict__ b3,
    const float* __restrict__ g3,  const float* __restrict__ bb3,
    const float* __restrict__ m3,  const float* __restrict__ v3,
    const float* __restrict__ W4,  const float* __restrict__ b4,
    float* __restrict__ out, int B, int ntiles)
{
    // 4 per-slot private LDS buffers: 8000 B each = 32000 B/block (1 wave/block)
    __shared__ __align__(16) char smem_raw[32000];
    const int lane = threadIdx.x & 63;
    const int l15  = lane & 15;
    const int quad = lane >> 4;
    const int qh   = quad >> 1;

    constexpr unsigned long long GS = packGS();
    constexpr unsigned GL = packGL();

    // ================= prologue: B-frags + per-lane params (L2-resident) ========
    f16x8 Benc[6];
    #pragma unroll
    for (int t = 0; t < 6; ++t) {
        const int n = t*16 + l15;
        const int g = n >> 3, o = n & 7;
        const int gs = (int)((GS >> (5*g)) & 31);
        const int gl = (int)((GL >> (2*g)) & 3);
        #pragma unroll
        for (int j = 0; j < 8; ++j) {
            const int k  = quad*8 + j;
            const int ji = k - gs;
            Benc[t][j] = (_Float16)((ji >= 0 && ji < gl) ? We[(g*3 + ji)*8 + o] : 0.f);
        }
    }
    f16x8 Bwa[3];
    #pragma unroll
    for (int s = 0; s < 3; ++s)
        #pragma unroll
        for (int j = 0; j < 8; ++j) {
            const int n = perm96(s*32 + quad*8 + j);
            Bwa[s][j] = (_Float16)((l15 < 12) ? Wa[n*12 + l15] : 0.f);
        }
    f16x8 Bw1[12];
    #pragma unroll
    for (int t = 0; t < 4; ++t)
        #pragma unroll
        for (int s = 0; s < 3; ++s)
            #pragma unroll
            for (int j = 0; j < 8; ++j) {
                const int n = perm96(s*32 + quad*8 + j);
                Bw1[t*3 + s][j] = (_Float16)W1[n*64 + t*16 + l15];
            }
    f16x8 Bw2[4];
    #pragma unroll
    for (int t = 0; t < 2; ++t)
        #pragma unroll
        for (int s = 0; s < 2; ++s)
            #pragma unroll
            for (int j = 0; j < 8; ++j) {
                const int n = perm64(s*32 + quad*8 + j);
                Bw2[t*2 + s][j] = (_Float16)W2[n*32 + t*16 + l15];
            }
    f16x8 Bw3;
    #pragma unroll
    for (int j = 0; j < 8; ++j)
        Bw3[j] = (_Float16)W3[perm32(quad*8 + j)*16 + l15];

    float encB[6], encS[6], encT[6];
    #pragma unroll
    for (int t = 0; t < 6; ++t) {
        const int c = t*16 + l15;
        float s = eg[c] * rsqrtf(ev[c] + EPS);
        encS[t] = s; encT[t] = ebt[c] - em[c]*s; encB[t] = be[c];
    }
    const float baL = (l15 < 12) ? ba[l15] : -1e4f;   // exp(-1e4)=0: pad cols drop out
    float b1L[4], s1L[4], t1L[4];
    #pragma unroll
    for (int t = 0; t < 4; ++t) {
        const int c = t*16 + l15;
        float s = g1[c] * rsqrtf(v1[c] + EPS);
        s1L[t] = s; t1L[t] = bb1[c] - m1[c]*s; b1L[t] = b1[c];
    }
    float b2L[2], s2L[2], t2L[2];
    #pragma unroll
    for (int t = 0; t < 2; ++t) {
        const int c = t*16 + l15;
        float s = g2[c] * rsqrtf(v2[c] + EPS);
        s2L[t] = s; t2L[t] = bb2[c] - m2[c]*s; b2L[t] = b2[c];
    }
    const float sv3 = g3[l15] * rsqrtf(v3[l15] + EPS);
    const float b3L = b3[l15], s3L = sv3, t3L = bb3[l15] - m3[l15]*sv3;
    const float w4L = W4[l15];
    const float b4v = b4[0];

    // ================= main loop: 32 tiles/wave = 8 groups x 4 slots =============
    const int tbase = blockIdx.x * 32;

    auto loadgrp = [&](int grp, float (&xv)[NSLOT][8]) {
        #pragma unroll
        for (int u = 0; u < NSLOT; ++u) {
            int tl = tbase + grp*NSLOT + u; if (tl > ntiles-1) tl = ntiles-1;
            int xr = tl*16 + l15; if (xr > B-1) xr = B-1;
            const float* xp = x + (size_t)xr*29 + quad*8;
            if (quad < 3) {
                #pragma unroll
                for (int j = 0; j < 8; ++j) xv[u][j] = xp[j];
            } else {
                #pragma unroll
                for (int j = 0; j < 5; ++j) xv[u][j] = xp[j];
                xv[u][5] = xv[u][6] = xv[u][7] = 0.f;
            }
        }
    };

    float xn[NSLOT][8];
    loadgrp(0, xn);

    #pragma unroll 1
    for (int p = 0; p < 8; ++p) {
        // consume prefetched x -> f16 A-frags, then prefetch next group
        f16x8 ax[NSLOT];
        #pragma unroll
        for (int u = 0; u < NSLOT; ++u)
            #pragma unroll
            for (int j = 0; j < 8; ++j) ax[u][j] = (_Float16)xn[u][j];
        loadgrp(p < 7 ? p + 1 : 7, xn);

        // ---- stage 1 (all slots): rep = BNaff(relu(x @ Wenc + be)) -> LDS ----
        #pragma unroll
        for (int u = 0; u < NSLOT; ++u) {
            _Float16* rep = (_Float16*)(smem_raw + u * 8000);
            #pragma unroll
            for (int tp = 0; tp < 3; ++tp) {
                f32x4 ca = { encB[tp],   encB[tp],   encB[tp],   encB[tp]   };
                f32x4 cb = { encB[tp+3], encB[tp+3], encB[tp+3], encB[tp+3] };
                ca = __builtin_amdgcn_mfma_f32_16x16x32_f16(ax[u], Benc[tp],   ca, 0, 0, 0);
                cb = __builtin_amdgcn_mfma_f32_16x16x32_f16(ax[u], Benc[tp+3], cb, 0, 0, 0);
                #pragma unroll
                for (int r = 0; r < 4; ++r) {
                    float va = fmaf(fmaxf(ca[r], 0.f), encS[tp],   encT[tp]);
                    float vb = fmaf(fmaxf(cb[r], 0.f), encS[tp+3], encT[tp+3]);
                    *(f16x2*)(rep + (quad*4 + r)*104 + tp*32 + l15*2) = pkrtz(va, vb);
                }
            }
        }

        // ---- read rep A-frags (all slots; shared by stages 2 and 3) ----
        f16x8 afr[NSLOT][3];
        #pragma unroll
        for (int u = 0; u < NSLOT; ++u) {
            const _Float16* rep = (const _Float16*)(smem_raw + u * 8000);
            #pragma unroll
            for (int s = 0; s < 3; ++s)
                afr[u][s] = *(const f16x8*)(rep + l15*104 + s*32 + quad*8);
        }

        // ---- stage 2 (all slots): logits + softmax (no max-sub; DPP row sum) ----
        #pragma unroll
        for (int u = 0; u < NSLOT; ++u) {
            float* wTb = (float*)(smem_raw + u * 8000 + 3328);
            f32x4 c2 = { baL, baL, baL, baL };
            #pragma unroll
            for (int s = 0; s < 3; ++s)
                c2 = __builtin_amdgcn_mfma_f32_16x16x32_f16(afr[u][s], Bwa[s], c2, 0, 0, 0);
            #pragma unroll
            for (int r = 0; r < 4; ++r) {
                float e  = __expf(c2[r]);
                float sm = row_sum16(e);
                wTb[(quad*4 + r)*17 + l15] = e * rcp_fast(sm);
            }
        }

        // ---- stage 3 (all slots): h1 = BNaff(relu((rep .* w) @ W1 + b1)) ----
        #pragma unroll
        for (int u = 0; u < NSLOT; ++u) {
            const float* wTb = (const float*)(smem_raw + u * 8000 + 3328);
            _Float16* h1b = (_Float16*)(smem_raw + u * 8000 + 4416);
            f32x4 c3[4];
            #pragma unroll
            for (int t = 0; t < 4; ++t) c3[t] = { b1L[t], b1L[t], b1L[t], b1L[t] };
            #pragma unroll
            for (int s = 0; s < 3; ++s) {
                float we = wTb[l15*17 + 2*s + qh];
                float wo = wTb[l15*17 + 2*s + 6 + qh];
                f16x2 wpk = pkrtz(we, wo);
                f16x8 wv = { wpk[0], wpk[1], wpk[0], wpk[1],
                             wpk[0], wpk[1], wpk[0], wpk[1] };
                f16x8 aw = afr[u][s] * wv;
                #pragma unroll
                for (int t = 0; t < 4; ++t)
                    c3[t] = __builtin_amdgcn_mfma_f32_16x16x32_f16(aw, Bw1[t*3 + s], c3[t], 0, 0, 0);
            }
            #pragma unroll
            for (int r = 0; r < 4; ++r) {
                float v0  = fmaf(fmaxf(c3[0][r], 0.f), s1L[0], t1L[0]);
                float v1_ = fmaf(fmaxf(c3[1][r], 0.f), s1L[1], t1L[1]);
                float v2_ = fmaf(fmaxf(c3[2][r], 0.f), s1L[2], t1L[2]);
                float v3_ = fmaf(fmaxf(c3[3][r], 0.f), s1L[3], t1L[3]);
                f16x2 p0 = pkrtz(v0,  v1_);
                f16x2 p1 = pkrtz(v2_, v3_);
                f16x4 pk = { p0[0], p0[1], p1[0], p1[1] };
                *(f16x4*)(h1b + (quad*4 + r)*72 + l15*4) = pk;
            }
        }

        // ---- stage 4 (all slots): h2 = BNaff(relu(h1 @ W2 + b2)) ----
        #pragma unroll
        for (int u = 0; u < NSLOT; ++u) {
            const _Float16* h1b = (const _Float16*)(smem_raw + u * 8000 + 4416);
            _Float16* h2b = (_Float16*)(smem_raw + u * 8000 + 6720);
            f32x4 c4[2];
            #pragma unroll
            for (int t = 0; t < 2; ++t) c4[t] = { b2L[t], b2L[t], b2L[t], b2L[t] };
            #pragma unroll
            for (int s = 0; s < 2; ++s) {
                f16x8 a = *(const f16x8*)(h1b + l15*72 + s*32 + quad*8);
                #pragma unroll
                for (int t = 0; t < 2; ++t)
                    c4[t] = __builtin_amdgcn_mfma_f32_16x16x32_f16(a, Bw2[t*2 + s], c4[t], 0, 0, 0);
            }
            #pragma unroll
            for (int r = 0; r < 4; ++r) {
                float v0  = fmaf(fmaxf(c4[0][r], 0.f), s2L[0], t2L[0]);
                float v1_ = fmaf(fmaxf(c4[1][r], 0.f), s2L[1], t2L[1]);
                *(f16x2*)(h2b + (quad*4 + r)*40 + l15*2) = pkrtz(v0, v1_);
            }
        }

        // ---- stages 5+6 (all slots): h3 MFMA; z = bnrelu(h3).W4; sigmoid ----
        #pragma unroll
        for (int u = 0; u < NSLOT; ++u) {
            const _Float16* h2b = (const _Float16*)(smem_raw + u * 8000 + 6720);
            f32x4 c5 = { b3L, b3L, b3L, b3L };
            f16x8 a = *(const f16x8*)(h2b + l15*40 + quad*8);
            c5 = __builtin_amdgcn_mfma_f32_16x16x32_f16(a, Bw3, c5, 0, 0, 0);

            float z[4];
            #pragma unroll
            for (int r = 0; r < 4; ++r) {
                float v = fmaf(fmaxf(c5[r], 0.f), s3L, t3L);
                z[r] = row_sum16(v * w4L);
            }
            const int tl = tbase + p*NSLOT + u;
            if (l15 == 0 && tl < ntiles) {
                const int row = tl*16 + quad*4;
                if (row + 3 < B) {
                    float4 o;
                    o.x = rcp_fast(1.f + __expf(-(z[0] + b4v)));
                    o.y = rcp_fast(1.f + __expf(-(z[1] + b4v)));
                    o.z = rcp_fast(1.f + __expf(-(z[2] + b4v)));
                    o.w = rcp_fast(1.f + __expf(-(z[3] + b4v)));
                    *(float4*)(out + row) = o;
                } else {
                    #pragma unroll
                    for (int r = 0; r < 4; ++r)
                        if (row + r < B)
                            out[row + r] = rcp_fast(1.f + __expf(-(z[r] + b4v)));
                }
            }
        }
    }
}

extern "C" void kernel_launch(void* const* d_in, const int* in_sizes, int n_in,
                              void* d_out, int out_size, void* d_ws, size_t ws_size,
                              hipStream_t stream)
{
    const float* x   = (const float*)d_in[0];
    const float* We  = (const float*)d_in[1];
    const float* be  = (const float*)d_in[2];
    const float* eg  = (const float*)d_in[3];
    const float* ebt = (const float*)d_in[4];
    const float* em  = (const float*)d_in[5];
    const float* ev  = (const float*)d_in[6];
    const float* Wa  = (const float*)d_in[7];
    const float* ba  = (const float*)d_in[8];
    const float* W1  = (const float*)d_in[9];
    const float* b1  = (const float*)d_in[10];
    const float* g1  = (const float*)d_in[11];
    const float* bb1 = (const float*)d_in[12];
    const float* m1  = (const float*)d_in[13];
    const float* v1  = (const float*)d_in[14];
    const float* W2  = (const float*)d_in[15];
    const float* b2  = (const float*)d_in[16];
    const float* g2  = (const float*)d_in[17];
    const float* bb2 = (const float*)d_in[18];
    const float* m2  = (const float*)d_in[19];
    const float* v2  = (const float*)d_in[20];
    const float* W3  = (const float*)d_in[21];
    const float* b3  = (const float*)d_in[22];
    const float* g3  = (const float*)d_in[23];
    const float* bb3 = (const float*)d_in[24];
    const float* m3  = (const float*)d_in[25];
    const float* v3  = (const float*)d_in[26];
    const float* W4  = (const float*)d_in[27];
    const float* b4  = (const float*)d_in[28];

    const int B = in_sizes[0] / 29;
    const int ntiles = (B + 15) / 16;
    const int blocks = (ntiles + 31) / 32;   // 32 tiles per single-wave block

    fused_kernel<<<blocks, 64, 0, stream>>>(
        x, We, be, eg, ebt, em, ev, Wa, ba,
        W1, b1, g1, bb1, m1, v1,
        W2, b2, g2, bb2, m2, v2,
        W3, b3, g3, bb3, m3, v3,
        W4, b4, (float*)d_out, B, ntiles);
}